// Round 3
// baseline (243.827 us; speedup 1.0000x reference)
//
#include <hip/hip_runtime.h>

#define OUT_DIM 4096
#define DPC     16
#define NCOL    65536    // OUT_DIM * DPC
#define BATCH   512

typedef float nvec4 __attribute__((ext_vector_type(4)));   // clang-native f32x4

// Kernel 1: bf[p] = exp((1/16 - duty[p]) * bs), double-prec exp rounded to fp32
// (bit-exact vs jnp.exp; table is 256 KiB -> L2-resident for kernel 2)
__global__ void boost_table_kernel(const float* __restrict__ duty,
                                   const float* __restrict__ bs_ptr,
                                   float* __restrict__ bf) {
    int p = blockIdx.x * blockDim.x + threadIdx.x;
    if (p < NCOL) {
        float t = (0.0625f - duty[p]) * bs_ptr[0];
        bf[p] = (float)exp((double)t);
    }
}

// Kernel 2: SINGLE-READ restructure. Block = (row r, quarter b): 1024 windows.
//   window-input span (stride-15): [15360b, 15360b+15376)
//   out-value span   (stride-16): [16384b, 16384b+16384)
//   union is contiguous: [15360b, 16384(b+1)), 16384+1024b <= 19456 floats.
// Stage the union ONCE (global_load_lds, 16B/lane), then:
//   P2: raw out-span x -> 8xfloat4 registers per thread (lane-consecutive f4)
//   P3: boost input span IN PLACE in LDS (x *= bf, bf from L2, coalesced f4)
//   P4a: stride-15 argmax per window (2-way bank = free), winner j -> byte LDS
//   P4b: mask registers by winner, coalesced NT float4 stores
// x HBM reads drop from 1.94x to 1.09x of the array.
__global__ __launch_bounds__(512, 4) void dkw_kernel(const float* __restrict__ x,
                                                     const float* __restrict__ bf,
                                                     float* __restrict__ out) {
    __shared__ float sx[19456];            // union span, 76 KiB (max, b=3)
    __shared__ unsigned char sjb[1024];    // winner j per window, 1 KiB
    // 77 KiB/block -> 2 blocks/CU (154 KiB of 160)

    const int tid = threadIdx.x;           // 0..511 (8 waves)
    const int r   = blockIdx.x >> 2;       // row
    const int b   = blockIdx.x & 3;        // quarter within row
    const int rowbase = r << 16;           // r * 65536
    const int span_f  = b * 15360;         // union start (row-local floats)
    const int S4      = 4096 + (b << 8);   // union length in float4s

    const float4* __restrict__ xg4 = (const float4*)(x + rowbase + span_f);
    float4* sx4 = (float4*)sx;

    // ---- P1: stage raw x union span -> LDS, async direct-to-LDS ----
    // i = wv*64 + lane + 512k: lane-consecutive global f4s, LDS dest =
    // wave-uniform base + lane*16 (exactly the HW pattern). S4 % 64 == 0,
    // so the bound check is wave-uniform.
    for (int i = tid; i < S4; i += 512) {
        __builtin_amdgcn_global_load_lds(
            (const __attribute__((address_space(1))) void*)(xg4 + i),
            (__attribute__((address_space(3))) void*)(sx4 + i), 16, 0, 0);
    }
    __syncthreads();

    // ---- P2: raw out-span values -> registers ----
    // out span = union f4 range [256b, 256b+4096); thread owns f4s tid+512k.
    float4 xo[8];
    #pragma unroll
    for (int k = 0; k < 8; ++k)
        xo[k] = sx4[(b << 8) + tid + (k << 9)];
    __syncthreads();   // all raw reads done before in-place boost below

    // ---- P3: boost input span in place: sx[0..15376) *= bf[span_f..] ----
    {
        const float4* __restrict__ bg4 = (const float4*)(bf + span_f);
        for (int i = tid; i < 3844; i += 512) {   // 15376 floats
            float4 a = sx4[i];
            float4 c = bg4[i];
            a.x *= c.x; a.y *= c.y; a.z *= c.z; a.w *= c.w;
            sx4[i] = a;
        }
    }
    __syncthreads();

    // ---- P4a: argmax for windows w = tid, tid+512 (stride-15 floats) ----
    #pragma unroll
    for (int m = 0; m < 2; ++m) {
        const int w = tid + (m << 9);
        const float* __restrict__ p = sx + w * 15;   // 2-way bank = free
        float best = p[0];
        int   bj   = 0;
        #pragma unroll
        for (int kk = 1; kk < DPC; ++kk) {
            float v = p[kk];
            if (v > best) { best = v; bj = kk; }     // strict > : first max wins
        }
        sjb[w] = (unsigned char)bj;
    }
    __syncthreads();

    // ---- P4b: mask registers by winner, coalesced NT stores ----
    float4* __restrict__ og4 = (float4*)(out + rowbase + (b << 14));
    #pragma unroll
    for (int k = 0; k < 8; ++k) {
        const int o4 = tid + (k << 9);               // out f4 index in quarter
        const int jm = (int)sjb[o4 >> 2];            // window of this f4
        const int j0 = (o4 & 3) << 2;                // first slot of this f4
        const float4 v = xo[k];
        float4 o;
        o.x = (j0     == jm) ? v.x : 0.0f;
        o.y = (j0 + 1 == jm) ? v.y : 0.0f;
        o.z = (j0 + 2 == jm) ? v.z : 0.0f;
        o.w = (j0 + 3 == jm) ? v.w : 0.0f;
        __builtin_nontemporal_store(*(const nvec4*)&o, (nvec4*)&og4[o4]);
    }
}

extern "C" void kernel_launch(void* const* d_in, const int* in_sizes, int n_in,
                              void* d_out, int out_size, void* d_ws, size_t ws_size,
                              hipStream_t stream) {
    const float* x    = (const float*)d_in[0];
    const float* duty = (const float*)d_in[1];
    const float* bs   = (const float*)d_in[2];
    float* out = (float*)d_out;
    float* bf  = (float*)d_ws;   // 65536 floats = 256 KiB scratch

    hipLaunchKernelGGL(boost_table_kernel, dim3(NCOL / 256), dim3(256), 0, stream,
                       duty, bs, bf);
    hipLaunchKernelGGL(dkw_kernel, dim3(BATCH * 4), dim3(512), 0, stream,
                       x, bf, out);
}

// Round 4
// 243.769 us; speedup vs baseline: 1.0002x; 1.0002x over previous
//
#include <hip/hip_runtime.h>

#define OUT_DIM 4096
#define DPC     16
#define NCOL    65536    // OUT_DIM * DPC
#define BATCH   512

typedef float nvec4 __attribute__((ext_vector_type(4)));   // clang-native f32x4

// Kernel 1: bf[p] = exp((1/16 - duty[p]) * bs), double-prec exp rounded to fp32
// (bit-exact vs jnp.exp; table is 256 KiB -> L2-resident for kernel 2)
__global__ void boost_table_kernel(const float* __restrict__ duty,
                                   const float* __restrict__ bs_ptr,
                                   float* __restrict__ bf) {
    int p = blockIdx.x * blockDim.x + threadIdx.x;
    if (p < NCOL) {
        float t = (0.0625f - duty[p]) * bs_ptr[0];
        bf[p] = (float)exp((double)t);
    }
}

// Kernel 2: low-traffic AND low-latency. Block = (row r, quarter b), 1024 windows.
//   - P1: reg-stage input span [15360b, 15360b+16384) with boost FUSED:
//         x f4 * bf f4 -> ds_write. 8 f4/thread, fully unrolled. LDS = 64 KiB.
//         (over-stages past the 15376 useful floats; pad is never read.
//          in-bounds: b=3 ends at float 62463 < 65536)
//   - P2: issue out-span x loads (coalesced f4 -> regs). Out span
//         [16384b, +16384) overlaps the just-staged input span by 94-100%,
//         so these are same-XCD L2 hits, unlike the distant-block reread of
//         earlier versions. Latency hides under the argmax (consume in P3).
//         Then stride-15 argmax from LDS (15l mod 32: lanes l, l+32 share a
//         bank -> 2-way = free), winner j -> byte table.
//   - P3: mask registers by winner, coalesced NT f4 stores.
// 2 barriers total (was 4), no union staging, no in-place LDS RMW.
// 65 KiB LDS -> 2 blocks/CU, 16 waves/CU ping-ponging stage vs compute.
__global__ __launch_bounds__(512, 4) void dkw_kernel(const float* __restrict__ x,
                                                     const float* __restrict__ bf,
                                                     float* __restrict__ out) {
    __shared__ float sb[16384];            // boosted input span, 64 KiB
    __shared__ unsigned char sjb[1024];    // winner j per window, 1 KiB

    const int tid = threadIdx.x;           // 0..511 (8 waves)
    const int r   = blockIdx.x >> 2;       // row
    const int b   = blockIdx.x & 3;        // quarter within row
    const int rowbase = r << 16;           // r * 65536
    const int span_f  = b * 15360;         // input span start (row-local)

    // ---- P1: fused boost + stage, 8 f4/thread ----
    const float4* __restrict__ xg4 = (const float4*)(x + rowbase + span_f);
    const float4* __restrict__ bg4 = (const float4*)(bf + span_f);
    float4* sb4 = (float4*)sb;
    #pragma unroll
    for (int k = 0; k < 8; ++k) {
        const int i = tid + (k << 9);      // lane-consecutive f4s
        float4 a = xg4[i];
        float4 c = bg4[i];
        a.x *= c.x; a.y *= c.y; a.z *= c.z; a.w *= c.w;
        sb4[i] = a;                        // conflict-free ds_write_b128
    }
    __syncthreads();

    // ---- P2: out-span x -> regs (L2-hot, consumed in P3), then argmax ----
    const float4* __restrict__ xo_g = (const float4*)(x + rowbase + (b << 14));
    float4 xo[8];
    #pragma unroll
    for (int k = 0; k < 8; ++k)
        xo[k] = xo_g[tid + (k << 9)];

    #pragma unroll
    for (int m = 0; m < 2; ++m) {
        const int w = tid + (m << 9);                // windows tid, tid+512
        const float* __restrict__ p = sb + w * 15;   // stride-15: 2-way bank = free
        float best = p[0];
        int   bj   = 0;
        #pragma unroll
        for (int kk = 1; kk < DPC; ++kk) {
            float v = p[kk];
            if (v > best) { best = v; bj = kk; }     // strict > : first max wins
        }
        sjb[w] = (unsigned char)bj;
    }
    __syncthreads();

    // ---- P3: mask registers by winner, coalesced NT stores ----
    float4* __restrict__ og4 = (float4*)(out + rowbase + (b << 14));
    #pragma unroll
    for (int k = 0; k < 8; ++k) {
        const int o4 = tid + (k << 9);               // out f4 index in quarter
        const int jm = (int)sjb[o4 >> 2];            // same-word byte reads: broadcast
        const int j0 = (o4 & 3) << 2;                // first slot of this f4
        const float4 v = xo[k];
        float4 o;
        o.x = (j0     == jm) ? v.x : 0.0f;
        o.y = (j0 + 1 == jm) ? v.y : 0.0f;
        o.z = (j0 + 2 == jm) ? v.z : 0.0f;
        o.w = (j0 + 3 == jm) ? v.w : 0.0f;
        __builtin_nontemporal_store(*(const nvec4*)&o, (nvec4*)&og4[o4]);
    }
}

extern "C" void kernel_launch(void* const* d_in, const int* in_sizes, int n_in,
                              void* d_out, int out_size, void* d_ws, size_t ws_size,
                              hipStream_t stream) {
    const float* x    = (const float*)d_in[0];
    const float* duty = (const float*)d_in[1];
    const float* bs   = (const float*)d_in[2];
    float* out = (float*)d_out;
    float* bf  = (float*)d_ws;   // 65536 floats = 256 KiB scratch

    hipLaunchKernelGGL(boost_table_kernel, dim3(NCOL / 256), dim3(256), 0, stream,
                       duty, bs, bf);
    hipLaunchKernelGGL(dkw_kernel, dim3(BATCH * 4), dim3(512), 0, stream,
                       x, bf, out);
}